// Round 9
// baseline (2243.139 us; speedup 1.0000x reference)
//
#include <hip/hip_runtime.h>
#include <math.h>

#define NB     16384
#define NTOT   427
#define NROI   30
#define TDIM   10
#define HDIM   64
#define FCD    32
#define NHD    256
#define NROIF  300
#define NOTHER 127
#define ACTD   31
#define NSEQ   (NB*NROI)
#define COMB   1216
#define LOG2E  1.44269504f

typedef __attribute__((ext_vector_type(8))) short bf16x8;
typedef __attribute__((ext_vector_type(4))) float f32x4;
typedef __attribute__((ext_vector_type(2))) float f32x2;

// ---------------------------------------------------------------------------
// ROOT CAUSE of R4/R5/R7/R8 failures (theory): CDNA TRANS-op use hazard.
// v_exp_f32 / v_rcp_f32 results need compiler-inserted wait states before a
// dependent VALU read; LLVM's hazard recognizer cannot see inside INLINEASM,
// so hand-written asm trans ops were hazard-unprotected — corruption appeared
// or vanished with unrelated scheduling changes (pk-asm body, hreg, lb(256,5)).
// Fix: intrinsics only — backend knows the opcode and inserts the nops.
// NO value-producing inline asm anywhere in this file.
// ---------------------------------------------------------------------------
#if __has_builtin(__builtin_amdgcn_exp2f)
__device__ __forceinline__ float fexp2(float x){ return __builtin_amdgcn_exp2f(x); }
#else
__device__ __forceinline__ float fexp2(float x){ return exp2f(x); }
#endif
#if __has_builtin(__builtin_amdgcn_rcpf)
__device__ __forceinline__ float frcp(float x){ return __builtin_amdgcn_rcpf(x); }
#else
__device__ __forceinline__ float frcp(float x){ return 1.0f / x; }
#endif
__device__ __forceinline__ f32x2 exp2v(f32x2 v){ f32x2 r; r.x = fexp2(v.x); r.y = fexp2(v.y); return r; }

// RNE f32->bf16 (explicit; v_cvt_pk_bf16_f32 is not RNE — R4 lesson)
__device__ __forceinline__ short f2bf(float f) {
    unsigned u = __builtin_bit_cast(unsigned, f);
    u += 0x7fff + ((u >> 16) & 1);
    return (short)(u >> 16);
}
__device__ __forceinline__ float bf2f(short s) {
    return __builtin_bit_cast(float, ((unsigned)(unsigned short)s) << 16);
}

// ---------------------------------------------------------------------------
// MLP layer: out[M=16384][256] = relu(in[M][K] @ W^T + b)   (fp32, unchanged)
// ---------------------------------------------------------------------------
template<int KDIM>
__global__ __launch_bounds__(256) void mlp_kernel(
    const float* __restrict__ in, int ld_in,
    const float* __restrict__ W, const float* __restrict__ bias,
    float* __restrict__ out, int ld_out)
{
    __shared__ float in_t[32][68];
    __shared__ float w_t[32][260];

    const int tid = threadIdx.x;
    const int m0  = blockIdx.x * 64;
    const int a   = tid & 7;
    const int bc  = tid >> 3;

    float acc[8][8];
    #pragma unroll
    for (int i = 0; i < 8; i++)
        #pragma unroll
        for (int jj = 0; jj < 8; jj++) acc[i][jj] = 0.0f;

    for (int k0 = 0; k0 < KDIM; k0 += 32) {
        __syncthreads();
        #pragma unroll
        for (int e = 0; e < 8; e++) {
            int idx = tid + e * 256;
            int k = idx & 31, m = idx >> 5;
            float v = 0.0f;
            if ((KDIM % 32 == 0) || (k0 + k < KDIM))
                v = in[(size_t)(m0 + m) * ld_in + k0 + k];
            in_t[k][m] = v;
        }
        {
            const int j = tid;
            #pragma unroll
            for (int e = 0; e < 8; e++) {
                #pragma unroll
                for (int qq = 0; qq < 4; qq++) {
                    int k = e * 4 + qq;
                    float v = 0.0f;
                    if ((KDIM % 32 == 0) || (k0 + k < KDIM))
                        v = W[(size_t)j * KDIM + k0 + k];
                    w_t[k][j] = v;
                }
            }
        }
        __syncthreads();
        #pragma unroll 4
        for (int k = 0; k < 32; k++) {
            float av[8], wv[8];
            #pragma unroll
            for (int i = 0; i < 8; i++)  av[i] = in_t[k][a * 8 + i];
            #pragma unroll
            for (int jj = 0; jj < 8; jj++) wv[jj] = w_t[k][bc * 8 + jj];
            #pragma unroll
            for (int i = 0; i < 8; i++)
                #pragma unroll
                for (int jj = 0; jj < 8; jj++)
                    acc[i][jj] = __fmaf_rn(av[i], wv[jj], acc[i][jj]);
        }
    }

    float bv[8];
    #pragma unroll
    for (int jj = 0; jj < 8; jj++) bv[jj] = bias[bc * 8 + jj];
    #pragma unroll
    for (int i = 0; i < 8; i++) {
        float* orow = out + (size_t)(m0 + a * 8 + i) * ld_out + bc * 8;
        #pragma unroll
        for (int jj = 0; jj < 8; jj++) {
            float v = acc[i][jj] + bv[jj];
            orow[jj] = v > 0.0f ? v : 0.0f;
        }
    }
}

// ---------------------------------------------------------------------------
// Fused bidirectional LSTM + FC, MFMA + f32x2 cell math.
// R9 = R6 data path EXACTLY, with (a) trans ops via builtins (hazard-safe,
// see header) and (b) __launch_bounds__(256,5): 5 blocks/CU at 27.6KB LDS,
// occupancy 44% -> ~62%.
// ---------------------------------------------------------------------------
__global__ __launch_bounds__(256, 5) void lstm_fc_mfma(
    const float* __restrict__ x,
    const float* __restrict__ Wih_f, const float* __restrict__ Whh_f,
    const float* __restrict__ bih_f, const float* __restrict__ bhh_f,
    const float* __restrict__ Wih_b, const float* __restrict__ Whh_b,
    const float* __restrict__ bih_b, const float* __restrict__ bhh_b,
    const float* __restrict__ Wfc, const float* __restrict__ bfc,
    float* __restrict__ combined)
{
    __shared__ short Hbuf[3][64 * 64];   // 24 KB
    __shared__ float Xs[TDIM][64];       // 2.5 KB
    __shared__ int   lens_s[64];

    const int tid    = threadIdx.x;
    const int w      = tid >> 6;
    const int lane   = tid & 63;
    const int n0     = lane & 15;
    const int kq     = lane >> 4;
    const int s0base = blockIdx.x * 64;

    for (int idx = tid; idx < 64 * TDIM; idx += 256) {
        int s = idx & 63, t = idx >> 6;
        int gs = s0base + s;
        int row = gs / NROI, r = gs - row * NROI;
        Xs[t][s] = x[(size_t)row * NTOT + r * TDIM + t];
    }
    __syncthreads();
    if (tid < 64) {
        int c = 0;
        #pragma unroll
        for (int t = 0; t < TDIM; t++) c += (Xs[t][tid] != 0.0f) ? 1 : 0;
        lens_s[tid] = c;
    }
    for (int idx = tid; idx < 64 * 64; idx += 256) {
        Hbuf[0][idx] = 0; Hbuf[2][idx] = 0;
    }
    __syncthreads();

    // packed lens: lenpk[mt*2+pr] = len(cell r0) | len(cell r0+1)<<16
    int lenpk[8];
    #pragma unroll
    for (int i = 0; i < 8; i++) {
        const int c0 = 2 * i, c1 = 2 * i + 1;
        const int mA = (c0 >> 2) * 16 + kq * 4 + (c0 & 3);
        const int mB = (c1 >> 2) * 16 + kq * 4 + (c1 & 3);
        lenpk[i] = lens_s[mA] | (lens_s[mB] << 16);
    }

    const int ubase = w * 16 + n0;
    const int uhi = ubase >> 3, ulo = ubase & 7;

    for (int dir = 0; dir < 2; dir++) {
        const float* Whh  = dir ? Whh_b : Whh_f;
        const float* Wih  = dir ? Wih_b : Wih_f;
        const float* bihp = dir ? bih_b : bih_f;
        const float* bhhp = dir ? bhh_b : bhh_f;
        short* bufE = Hbuf[dir ? 2 : 0];
        short* bufO = Hbuf[1];

        // gate scales: q = gate type (i,f,g,o PyTorch order)
        const float sc0 = -LOG2E, sc2 = 2.0f * LOG2E;

        bf16x8 bfrag[4][2];
        float  wihS[4];
        f32x4  cinq[4];
        #pragma unroll
        for (int q = 0; q < 4; q++) {
            const float s_q = (q == 2) ? sc2 : sc0;
            const int n = (q * 4 + w) * 16 + n0;
            wihS[q] = s_q * Wih[n];
            const float bb = s_q * (bihp[n] + bhhp[n]);
            cinq[q][0] = bb; cinq[q][1] = bb; cinq[q][2] = bb; cinq[q][3] = bb;
            #pragma unroll
            for (int half = 0; half < 2; half++) {
                const float* src = Whh + (size_t)n * HDIM + half * 32 + kq * 8;
                bf16x8 f;
                #pragma unroll
                for (int j = 0; j < 8; j++) f[j] = f2bf(s_q * src[j]);
                bfrag[q][half] = f;
            }
        }

        f32x2 c2[8];
        #pragma unroll
        for (int i = 0; i < 8; i++) { c2[i].x = 0.0f; c2[i].y = 0.0f; }

        for (int step = 0; step < TDIM; step++) {
            const int t = dir ? (TDIM - 1 - step) : step;
            short* rb = (step & 1) ? bufO : bufE;
            short* wb = (step & 1) ? bufE : bufO;

            #pragma unroll
            for (int mt = 0; mt < 4; mt++) {
                const int ma = mt * 16 + n0;
                const int sa = ma & 7;
                bf16x8 a0 = *(const bf16x8*)&rb[ma * 64 + ((kq ^ sa) << 3)];
                bf16x8 a1 = *(const bf16x8*)&rb[ma * 64 + (((4 + kq) ^ sa) << 3)];

                f32x4 acc[4];
                #pragma unroll
                for (int q = 0; q < 4; q++) {
                    f32x4 p = __builtin_amdgcn_mfma_f32_16x16x32_bf16(a0, bfrag[q][0], cinq[q], 0, 0, 0);
                    acc[q] = __builtin_amdgcn_mfma_f32_16x16x32_bf16(a1, bfrag[q][1], p, 0, 0, 0);
                }

                #pragma unroll
                for (int pr = 0; pr < 2; pr++) {
                    const int r0  = 2 * pr;
                    const int mm  = mt * 16 + kq * 4 + r0;
                    const int lp  = lenpk[mt * 2 + pr];
                    const bool m0 = t < (lp & 0xffff);
                    const bool m1 = t < (lp >> 16);

                    f32x2 xv2 = *(const f32x2*)&Xs[t][mm];
                    f32x2 a_i = {acc[0][r0], acc[0][r0 + 1]};
                    f32x2 a_f = {acc[1][r0], acc[1][r0 + 1]};
                    f32x2 a_g = {acc[2][r0], acc[2][r0 + 1]};
                    f32x2 a_o = {acc[3][r0], acc[3][r0 + 1]};

                    // scaled gates -> exp2 directly (native vector math)
                    f32x2 ei = exp2v(a_i + xv2 * wihS[0]);
                    f32x2 ef = exp2v(a_f + xv2 * wihS[1]);
                    f32x2 eg = exp2v(a_g + xv2 * wihS[2]);
                    f32x2 eo = exp2v(a_o + xv2 * wihS[3]);

                    f32x2 di = ei + 1.0f;
                    f32x2 df = ef + 1.0f;
                    f32x2 dg = eg + 1.0f;
                    f32x2 dd = eo + 1.0f;

                    // batched reciprocal: 1 rcp per cell for 4 denominators
                    f32x2 t1 = di * df;
                    f32x2 t2 = dd * dg;
                    f32x2 P  = t1 * t2;
                    f32x2 R; R.x = frcp(P.x); R.y = frcp(P.y);
                    f32x2 R12 = R * t2;
                    f32x2 R34 = R * t1;
                    f32x2 si  = R12 * df;            // sigmoid(i)
                    f32x2 sf  = R12 * di;            // sigmoid(f)
                    f32x2 so  = R34 * dg;            // sigmoid(o)
                    f32x2 ig  = R34 * dd;            // 1/(1+e^{2g})
                    f32x2 tg  = 1.0f - 2.0f * ig;    // tanh(g)

                    f32x2 cp = c2[mt * 2 + pr];
                    f32x2 cn = si * tg + sf * cp;
                    f32x2 cf;
                    cf.x = m0 ? cn.x : cp.x;
                    cf.y = m1 ? cn.y : cp.y;
                    c2[mt * 2 + pr] = cf;

                    // tanh(c) with pair-batched rcp
                    f32x2 ec = exp2v(cf * (2.0f * LOG2E));
                    f32x2 dc = ec + 1.0f;
                    float Pc = dc.x * dc.y;
                    float Rc = frcp(Pc);
                    f32x2 invc; invc.x = Rc * dc.y; invc.y = Rc * dc.x;
                    f32x2 tc = 1.0f - 2.0f * invc;
                    f32x2 hn = so * tc;

                    const int hidx0 = (mm << 6)       + (((uhi ^ mm) & 7) << 3)       + ulo;
                    const int hidx1 = ((mm + 1) << 6) + (((uhi ^ (mm + 1)) & 7) << 3) + ulo;
                    float h0 = m0 ? hn.x : bf2f(rb[hidx0]);
                    float h1 = m1 ? hn.y : bf2f(rb[hidx1]);
                    wb[hidx0] = f2bf(h0);   // RNE — required
                    wb[hidx1] = f2bf(h1);
                }
            }
            __syncthreads();   // wb complete before it becomes next step's rb
        }
        // final h of this dir is in bufE (step 9 writes bufE)
    }

    __builtin_amdgcn_sched_barrier(0);

    // ---- FC epilogue as MFMA: D[64s x 32f] = [Hf|Hb][64x128] @ Wfc^T ----
    {
        const short* Hf = Hbuf[0];
        const short* Hb = Hbuf[2];

        bf16x8 wfr[2][4];
        float  bias[2];
        #pragma unroll
        for (int nt = 0; nt < 2; nt++) {
            const int f = nt * 16 + n0;
            bias[nt] = bfc[f];
            #pragma unroll
            for (int kc = 0; kc < 4; kc++) {
                const float* src = Wfc + (size_t)f * 128 + kc * 32 + kq * 8;
                bf16x8 v;
                #pragma unroll
                for (int j = 0; j < 8; j++) v[j] = f2bf(src[j]);
                wfr[nt][kc] = v;
            }
        }

        const int ma = w * 16 + n0;
        const int sa = ma & 7;
        bf16x8 afr[4];
        #pragma unroll
        for (int kc = 0; kc < 2; kc++) {
            afr[kc]     = *(const bf16x8*)&Hf[ma * 64 + (((kc * 4 + kq) ^ sa) << 3)];
            afr[kc + 2] = *(const bf16x8*)&Hb[ma * 64 + (((kc * 4 + kq) ^ sa) << 3)];
        }

        f32x4 acc[2];
        #pragma unroll
        for (int nt = 0; nt < 2; nt++) {
            f32x4 z = {0.0f, 0.0f, 0.0f, 0.0f};
            acc[nt] = z;
            #pragma unroll
            for (int kc = 0; kc < 4; kc++)
                acc[nt] = __builtin_amdgcn_mfma_f32_16x16x32_bf16(afr[kc], wfr[nt][kc], acc[nt], 0, 0, 0);
        }

        #pragma unroll
        for (int nt = 0; nt < 2; nt++) {
            #pragma unroll
            for (int r = 0; r < 4; r++) {
                const int s   = w * 16 + kq * 4 + r;
                const int gs  = s0base + s;
                const int row = gs / NROI, rr = gs - row * NROI;
                float v = acc[nt][r] + bias[nt];
                combined[(size_t)row * COMB + rr * FCD + nt * 16 + n0] = v > 0.0f ? v : 0.0f;
            }
        }
    }
}

// ---------------------------------------------------------------------------
// Output projection: q[row][j] = b_out[j] + combined[row] . W_out[j]
// ---------------------------------------------------------------------------
__global__ __launch_bounds__(256) void qout_kernel(
    const float* __restrict__ combined,
    const float* __restrict__ Wout,
    const float* __restrict__ bout,
    float* __restrict__ q)
{
    const int j   = threadIdx.x;              // 0..31 (31 masked)
    const int r   = threadIdx.y;              // 0..7
    const int row = blockIdx.x * 8 + r;
    if (j >= ACTD) return;
    const float4* crow = (const float4*)(combined + (size_t)row * COMB);
    const float4* wrow = (const float4*)(Wout + (size_t)j * COMB);
    float acc = bout[j];
    #pragma unroll 4
    for (int k4 = 0; k4 < COMB / 4; k4++) {
        float4 c4 = crow[k4];
        float4 w4 = wrow[k4];
        acc += c4.x * w4.x + c4.y * w4.y + c4.z * w4.z + c4.w * w4.w;
    }
    q[(size_t)row * ACTD + j] = acc;
}

// ---------------------------------------------------------------------------
extern "C" void kernel_launch(void* const* d_in, const int* in_sizes, int n_in,
                              void* d_out, int out_size, void* d_ws, size_t ws_size,
                              hipStream_t stream)
{
    (void)in_sizes; (void)n_in; (void)out_size;
    const float* x     = (const float*)d_in[0];
    const float* Wih_f = (const float*)d_in[1];
    const float* Whh_f = (const float*)d_in[2];
    const float* bih_f = (const float*)d_in[3];
    const float* bhh_f = (const float*)d_in[4];
    const float* Wih_b = (const float*)d_in[5];
    const float* Whh_b = (const float*)d_in[6];
    const float* bih_b = (const float*)d_in[7];
    const float* bhh_b = (const float*)d_in[8];
    const float* Wfc   = (const float*)d_in[9];
    const float* bfc   = (const float*)d_in[10];
    const float* W1    = (const float*)d_in[11];
    const float* b1    = (const float*)d_in[12];
    const float* W2    = (const float*)d_in[13];
    const float* b2    = (const float*)d_in[14];
    const float* W3    = (const float*)d_in[15];
    const float* b3    = (const float*)d_in[16];
    const float* Wout  = (const float*)d_in[17];
    const float* bout  = (const float*)d_in[18];
    float* q        = (float*)d_out;
    float* combined = (float*)d_ws;   // 16384 x 1216 f32 = 79.7 MB

    if (ws_size < (size_t)NB * COMB * sizeof(float)) return;

    mlp_kernel<NOTHER><<<NB / 64, 256, 0, stream>>>(x + NROIF, NTOT, W1, b1, combined, COMB);
    mlp_kernel<NHD><<<NB / 64, 256, 0, stream>>>(combined, COMB, W2, b2, combined + 256, COMB);
    mlp_kernel<NHD><<<NB / 64, 256, 0, stream>>>(combined + 256, COMB, W3, b3, combined + 960, COMB);

    lstm_fc_mfma<<<NSEQ / 64, 256, 0, stream>>>(x, Wih_f, Whh_f, bih_f, bhh_f,
                                                Wih_b, Whh_b, bih_b, bhh_b,
                                                Wfc, bfc, combined);

    qout_kernel<<<NB / 8, dim3(32, 8), 0, stream>>>(combined, Wout, bout, q);
}

// Round 10
// 1226.002 us; speedup vs baseline: 1.8296x; 1.8296x over previous
//
#include <hip/hip_runtime.h>
#include <math.h>

#define NB     16384
#define NTOT   427
#define NROI   30
#define TDIM   10
#define HDIM   64
#define FCD    32
#define NHD    256
#define NROIF  300
#define NOTHER 127
#define ACTD   31
#define NSEQ   (NB*NROI)
#define COMB   1216
#define LOG2E  1.44269504f

typedef __attribute__((ext_vector_type(8))) short bf16x8;
typedef __attribute__((ext_vector_type(4))) float f32x4;
typedef __attribute__((ext_vector_type(2))) float f32x2;

// ---------------------------------------------------------------------------
// Correctness history (do not regress):
//  - R4/R5/R7/R8 corruption: CDNA TRANS-op use hazard — value-producing
//    inline asm (v_exp/v_rcp/v_pk_*) is invisible to LLVM's hazard
//    recognizer. Fix: intrinsics ONLY. No value-producing inline asm.
//  - R9 perf cliff: __launch_bounds__(256,5) + schedulable builtins =>
//    peak reg pressure > 96-reg cap => GB-scale scratch spills
//    (FETCH_SIZE 74MB -> 3.6GB). Keep (256,4); watch FETCH_SIZE + VGPR_Count.
// ---------------------------------------------------------------------------
#if __has_builtin(__builtin_amdgcn_exp2f)
__device__ __forceinline__ float fexp2(float x){ return __builtin_amdgcn_exp2f(x); }
#else
__device__ __forceinline__ float fexp2(float x){ return exp2f(x); }
#endif
#if __has_builtin(__builtin_amdgcn_rcpf)
__device__ __forceinline__ float frcp(float x){ return __builtin_amdgcn_rcpf(x); }
#else
__device__ __forceinline__ float frcp(float x){ return 1.0f / x; }
#endif
__device__ __forceinline__ f32x2 exp2v(f32x2 v){ f32x2 r; r.x = fexp2(v.x); r.y = fexp2(v.y); return r; }

// RNE f32->bf16 (explicit; v_cvt_pk_bf16_f32 is not RNE — R4 lesson)
__device__ __forceinline__ short f2bf(float f) {
    unsigned u = __builtin_bit_cast(unsigned, f);
    u += 0x7fff + ((u >> 16) & 1);
    return (short)(u >> 16);
}
__device__ __forceinline__ float bf2f(short s) {
    return __builtin_bit_cast(float, ((unsigned)(unsigned short)s) << 16);
}

// ---------------------------------------------------------------------------
// MLP layer: out[M=16384][256] = relu(in[M][K] @ W^T + b)   (fp32, unchanged)
// ---------------------------------------------------------------------------
template<int KDIM>
__global__ __launch_bounds__(256) void mlp_kernel(
    const float* __restrict__ in, int ld_in,
    const float* __restrict__ W, const float* __restrict__ bias,
    float* __restrict__ out, int ld_out)
{
    __shared__ float in_t[32][68];
    __shared__ float w_t[32][260];

    const int tid = threadIdx.x;
    const int m0  = blockIdx.x * 64;
    const int a   = tid & 7;
    const int bc  = tid >> 3;

    float acc[8][8];
    #pragma unroll
    for (int i = 0; i < 8; i++)
        #pragma unroll
        for (int jj = 0; jj < 8; jj++) acc[i][jj] = 0.0f;

    for (int k0 = 0; k0 < KDIM; k0 += 32) {
        __syncthreads();
        #pragma unroll
        for (int e = 0; e < 8; e++) {
            int idx = tid + e * 256;
            int k = idx & 31, m = idx >> 5;
            float v = 0.0f;
            if ((KDIM % 32 == 0) || (k0 + k < KDIM))
                v = in[(size_t)(m0 + m) * ld_in + k0 + k];
            in_t[k][m] = v;
        }
        {
            const int j = tid;
            #pragma unroll
            for (int e = 0; e < 8; e++) {
                #pragma unroll
                for (int qq = 0; qq < 4; qq++) {
                    int k = e * 4 + qq;
                    float v = 0.0f;
                    if ((KDIM % 32 == 0) || (k0 + k < KDIM))
                        v = W[(size_t)j * KDIM + k0 + k];
                    w_t[k][j] = v;
                }
            }
        }
        __syncthreads();
        #pragma unroll 4
        for (int k = 0; k < 32; k++) {
            float av[8], wv[8];
            #pragma unroll
            for (int i = 0; i < 8; i++)  av[i] = in_t[k][a * 8 + i];
            #pragma unroll
            for (int jj = 0; jj < 8; jj++) wv[jj] = w_t[k][bc * 8 + jj];
            #pragma unroll
            for (int i = 0; i < 8; i++)
                #pragma unroll
                for (int jj = 0; jj < 8; jj++)
                    acc[i][jj] = __fmaf_rn(av[i], wv[jj], acc[i][jj]);
        }
    }

    float bv[8];
    #pragma unroll
    for (int jj = 0; jj < 8; jj++) bv[jj] = bias[bc * 8 + jj];
    #pragma unroll
    for (int i = 0; i < 8; i++) {
        float* orow = out + (size_t)(m0 + a * 8 + i) * ld_out + bc * 8;
        #pragma unroll
        for (int jj = 0; jj < 8; jj++) {
            float v = acc[i][jj] + bv[jj];
            orow[jj] = v > 0.0f ? v : 0.0f;
        }
    }
}

// ---------------------------------------------------------------------------
// Fused bidirectional LSTM + FC, MFMA + f32x2 cell math.
// R10 = R9 data path EXACTLY (builtins, hazard-safe) with __launch_bounds__
// reverted to (256,4) — the (256,5) cap caused the R9 spill cliff.
// ---------------------------------------------------------------------------
__global__ __launch_bounds__(256, 4) void lstm_fc_mfma(
    const float* __restrict__ x,
    const float* __restrict__ Wih_f, const float* __restrict__ Whh_f,
    const float* __restrict__ bih_f, const float* __restrict__ bhh_f,
    const float* __restrict__ Wih_b, const float* __restrict__ Whh_b,
    const float* __restrict__ bih_b, const float* __restrict__ bhh_b,
    const float* __restrict__ Wfc, const float* __restrict__ bfc,
    float* __restrict__ combined)
{
    __shared__ short Hbuf[3][64 * 64];   // 24 KB
    __shared__ float Xs[TDIM][64];       // 2.5 KB
    __shared__ int   lens_s[64];

    const int tid    = threadIdx.x;
    const int w      = tid >> 6;
    const int lane   = tid & 63;
    const int n0     = lane & 15;
    const int kq     = lane >> 4;
    const int s0base = blockIdx.x * 64;

    for (int idx = tid; idx < 64 * TDIM; idx += 256) {
        int s = idx & 63, t = idx >> 6;
        int gs = s0base + s;
        int row = gs / NROI, r = gs - row * NROI;
        Xs[t][s] = x[(size_t)row * NTOT + r * TDIM + t];
    }
    __syncthreads();
    if (tid < 64) {
        int c = 0;
        #pragma unroll
        for (int t = 0; t < TDIM; t++) c += (Xs[t][tid] != 0.0f) ? 1 : 0;
        lens_s[tid] = c;
    }
    for (int idx = tid; idx < 64 * 64; idx += 256) {
        Hbuf[0][idx] = 0; Hbuf[2][idx] = 0;
    }
    __syncthreads();

    // packed lens: lenpk[mt*2+pr] = len(cell r0) | len(cell r0+1)<<16
    int lenpk[8];
    #pragma unroll
    for (int i = 0; i < 8; i++) {
        const int c0 = 2 * i, c1 = 2 * i + 1;
        const int mA = (c0 >> 2) * 16 + kq * 4 + (c0 & 3);
        const int mB = (c1 >> 2) * 16 + kq * 4 + (c1 & 3);
        lenpk[i] = lens_s[mA] | (lens_s[mB] << 16);
    }

    const int ubase = w * 16 + n0;
    const int uhi = ubase >> 3, ulo = ubase & 7;

    for (int dir = 0; dir < 2; dir++) {
        const float* Whh  = dir ? Whh_b : Whh_f;
        const float* Wih  = dir ? Wih_b : Wih_f;
        const float* bihp = dir ? bih_b : bih_f;
        const float* bhhp = dir ? bhh_b : bhh_f;
        short* bufE = Hbuf[dir ? 2 : 0];
        short* bufO = Hbuf[1];

        // gate scales: q = gate type (i,f,g,o PyTorch order)
        const float sc0 = -LOG2E, sc2 = 2.0f * LOG2E;

        bf16x8 bfrag[4][2];
        float  wihS[4];
        f32x4  cinq[4];
        #pragma unroll
        for (int q = 0; q < 4; q++) {
            const float s_q = (q == 2) ? sc2 : sc0;
            const int n = (q * 4 + w) * 16 + n0;
            wihS[q] = s_q * Wih[n];
            const float bb = s_q * (bihp[n] + bhhp[n]);
            cinq[q][0] = bb; cinq[q][1] = bb; cinq[q][2] = bb; cinq[q][3] = bb;
            #pragma unroll
            for (int half = 0; half < 2; half++) {
                const float* src = Whh + (size_t)n * HDIM + half * 32 + kq * 8;
                bf16x8 f;
                #pragma unroll
                for (int j = 0; j < 8; j++) f[j] = f2bf(s_q * src[j]);
                bfrag[q][half] = f;
            }
        }

        f32x2 c2[8];
        #pragma unroll
        for (int i = 0; i < 8; i++) { c2[i].x = 0.0f; c2[i].y = 0.0f; }

        for (int step = 0; step < TDIM; step++) {
            const int t = dir ? (TDIM - 1 - step) : step;
            short* rb = (step & 1) ? bufO : bufE;
            short* wb = (step & 1) ? bufE : bufO;

            #pragma unroll
            for (int mt = 0; mt < 4; mt++) {
                const int ma = mt * 16 + n0;
                const int sa = ma & 7;
                bf16x8 a0 = *(const bf16x8*)&rb[ma * 64 + ((kq ^ sa) << 3)];
                bf16x8 a1 = *(const bf16x8*)&rb[ma * 64 + (((4 + kq) ^ sa) << 3)];

                f32x4 acc[4];
                #pragma unroll
                for (int q = 0; q < 4; q++) {
                    f32x4 p = __builtin_amdgcn_mfma_f32_16x16x32_bf16(a0, bfrag[q][0], cinq[q], 0, 0, 0);
                    acc[q] = __builtin_amdgcn_mfma_f32_16x16x32_bf16(a1, bfrag[q][1], p, 0, 0, 0);
                }

                #pragma unroll
                for (int pr = 0; pr < 2; pr++) {
                    const int r0  = 2 * pr;
                    const int mm  = mt * 16 + kq * 4 + r0;
                    const int lp  = lenpk[mt * 2 + pr];
                    const bool m0 = t < (lp & 0xffff);
                    const bool m1 = t < (lp >> 16);

                    f32x2 xv2 = *(const f32x2*)&Xs[t][mm];
                    f32x2 a_i = {acc[0][r0], acc[0][r0 + 1]};
                    f32x2 a_f = {acc[1][r0], acc[1][r0 + 1]};
                    f32x2 a_g = {acc[2][r0], acc[2][r0 + 1]};
                    f32x2 a_o = {acc[3][r0], acc[3][r0 + 1]};

                    // scaled gates -> exp2 directly (native vector math)
                    f32x2 ei = exp2v(a_i + xv2 * wihS[0]);
                    f32x2 ef = exp2v(a_f + xv2 * wihS[1]);
                    f32x2 eg = exp2v(a_g + xv2 * wihS[2]);
                    f32x2 eo = exp2v(a_o + xv2 * wihS[3]);

                    f32x2 di = ei + 1.0f;
                    f32x2 df = ef + 1.0f;
                    f32x2 dg = eg + 1.0f;
                    f32x2 dd = eo + 1.0f;

                    // batched reciprocal: 1 rcp per cell for 4 denominators
                    f32x2 t1 = di * df;
                    f32x2 t2 = dd * dg;
                    f32x2 P  = t1 * t2;
                    f32x2 R; R.x = frcp(P.x); R.y = frcp(P.y);
                    f32x2 R12 = R * t2;
                    f32x2 R34 = R * t1;
                    f32x2 si  = R12 * df;            // sigmoid(i)
                    f32x2 sf  = R12 * di;            // sigmoid(f)
                    f32x2 so  = R34 * dg;            // sigmoid(o)
                    f32x2 ig  = R34 * dd;            // 1/(1+e^{2g})
                    f32x2 tg  = 1.0f - 2.0f * ig;    // tanh(g)

                    f32x2 cp = c2[mt * 2 + pr];
                    f32x2 cn = si * tg + sf * cp;
                    f32x2 cf;
                    cf.x = m0 ? cn.x : cp.x;
                    cf.y = m1 ? cn.y : cp.y;
                    c2[mt * 2 + pr] = cf;

                    // tanh(c) with pair-batched rcp
                    f32x2 ec = exp2v(cf * (2.0f * LOG2E));
                    f32x2 dc = ec + 1.0f;
                    float Pc = dc.x * dc.y;
                    float Rc = frcp(Pc);
                    f32x2 invc; invc.x = Rc * dc.y; invc.y = Rc * dc.x;
                    f32x2 tc = 1.0f - 2.0f * invc;
                    f32x2 hn = so * tc;

                    const int hidx0 = (mm << 6)       + (((uhi ^ mm) & 7) << 3)       + ulo;
                    const int hidx1 = ((mm + 1) << 6) + (((uhi ^ (mm + 1)) & 7) << 3) + ulo;
                    float h0 = m0 ? hn.x : bf2f(rb[hidx0]);
                    float h1 = m1 ? hn.y : bf2f(rb[hidx1]);
                    wb[hidx0] = f2bf(h0);   // RNE — required
                    wb[hidx1] = f2bf(h1);
                }
            }
            __syncthreads();   // wb complete before it becomes next step's rb
        }
        // final h of this dir is in bufE (step 9 writes bufE)
    }

    __builtin_amdgcn_sched_barrier(0);

    // ---- FC epilogue as MFMA: D[64s x 32f] = [Hf|Hb][64x128] @ Wfc^T ----
    {
        const short* Hf = Hbuf[0];
        const short* Hb = Hbuf[2];

        bf16x8 wfr[2][4];
        float  bias[2];
        #pragma unroll
        for (int nt = 0; nt < 2; nt++) {
            const int f = nt * 16 + n0;
            bias[nt] = bfc[f];
            #pragma unroll
            for (int kc = 0; kc < 4; kc++) {
                const float* src = Wfc + (size_t)f * 128 + kc * 32 + kq * 8;
                bf16x8 v;
                #pragma unroll
                for (int j = 0; j < 8; j++) v[j] = f2bf(src[j]);
                wfr[nt][kc] = v;
            }
        }

        const int ma = w * 16 + n0;
        const int sa = ma & 7;
        bf16x8 afr[4];
        #pragma unroll
        for (int kc = 0; kc < 2; kc++) {
            afr[kc]     = *(const bf16x8*)&Hf[ma * 64 + (((kc * 4 + kq) ^ sa) << 3)];
            afr[kc + 2] = *(const bf16x8*)&Hb[ma * 64 + (((kc * 4 + kq) ^ sa) << 3)];
        }

        f32x4 acc[2];
        #pragma unroll
        for (int nt = 0; nt < 2; nt++) {
            f32x4 z = {0.0f, 0.0f, 0.0f, 0.0f};
            acc[nt] = z;
            #pragma unroll
            for (int kc = 0; kc < 4; kc++)
                acc[nt] = __builtin_amdgcn_mfma_f32_16x16x32_bf16(afr[kc], wfr[nt][kc], acc[nt], 0, 0, 0);
        }

        #pragma unroll
        for (int nt = 0; nt < 2; nt++) {
            #pragma unroll
            for (int r = 0; r < 4; r++) {
                const int s   = w * 16 + kq * 4 + r;
                const int gs  = s0base + s;
                const int row = gs / NROI, rr = gs - row * NROI;
                float v = acc[nt][r] + bias[nt];
                combined[(size_t)row * COMB + rr * FCD + nt * 16 + n0] = v > 0.0f ? v : 0.0f;
            }
        }
    }
}

// ---------------------------------------------------------------------------
// Output projection: q[row][j] = b_out[j] + combined[row] . W_out[j]
// ---------------------------------------------------------------------------
__global__ __launch_bounds__(256) void qout_kernel(
    const float* __restrict__ combined,
    const float* __restrict__ Wout,
    const float* __restrict__ bout,
    float* __restrict__ q)
{
    const int j   = threadIdx.x;              // 0..31 (31 masked)
    const int r   = threadIdx.y;              // 0..7
    const int row = blockIdx.x * 8 + r;
    if (j >= ACTD) return;
    const float4* crow = (const float4*)(combined + (size_t)row * COMB);
    const float4* wrow = (const float4*)(Wout + (size_t)j * COMB);
    float acc = bout[j];
    #pragma unroll 4
    for (int k4 = 0; k4 < COMB / 4; k4++) {
        float4 c4 = crow[k4];
        float4 w4 = wrow[k4];
        acc += c4.x * w4.x + c4.y * w4.y + c4.z * w4.z + c4.w * w4.w;
    }
    q[(size_t)row * ACTD + j] = acc;
}

// ---------------------------------------------------------------------------
extern "C" void kernel_launch(void* const* d_in, const int* in_sizes, int n_in,
                              void* d_out, int out_size, void* d_ws, size_t ws_size,
                              hipStream_t stream)
{
    (void)in_sizes; (void)n_in; (void)out_size;
    const float* x     = (const float*)d_in[0];
    const float* Wih_f = (const float*)d_in[1];
    const float* Whh_f = (const float*)d_in[2];
    const float* bih_f = (const float*)d_in[3];
    const float* bhh_f = (const float*)d_in[4];
    const float* Wih_b = (const float*)d_in[5];
    const float* Whh_b = (const float*)d_in[6];
    const float* bih_b = (const float*)d_in[7];
    const float* bhh_b = (const float*)d_in[8];
    const float* Wfc   = (const float*)d_in[9];
    const float* bfc   = (const float*)d_in[10];
    const float* W1    = (const float*)d_in[11];
    const float* b1    = (const float*)d_in[12];
    const float* W2    = (const float*)d_in[13];
    const float* b2    = (const float*)d_in[14];
    const float* W3    = (const float*)d_in[15];
    const float* b3    = (const float*)d_in[16];
    const float* Wout  = (const float*)d_in[17];
    const float* bout  = (const float*)d_in[18];
    float* q        = (float*)d_out;
    float* combined = (float*)d_ws;   // 16384 x 1216 f32 = 79.7 MB

    if (ws_size < (size_t)NB * COMB * sizeof(float)) return;

    mlp_kernel<NOTHER><<<NB / 64, 256, 0, stream>>>(x + NROIF, NTOT, W1, b1, combined, COMB);
    mlp_kernel<NHD><<<NB / 64, 256, 0, stream>>>(combined, COMB, W2, b2, combined + 256, COMB);
    mlp_kernel<NHD><<<NB / 64, 256, 0, stream>>>(combined + 256, COMB, W3, b3, combined + 960, COMB);

    lstm_fc_mfma<<<NSEQ / 64, 256, 0, stream>>>(x, Wih_f, Whh_f, bih_f, bhh_f,
                                                Wih_b, Whh_b, bih_b, bhh_b,
                                                Wfc, bfc, combined);

    qout_kernel<<<NB / 8, dim3(32, 8), 0, stream>>>(combined, Wout, bout, q);
}

// Round 11
// 1157.238 us; speedup vs baseline: 1.9384x; 1.0594x over previous
//
#include <hip/hip_runtime.h>
#include <math.h>

#define NB     16384
#define NTOT   427
#define NROI   30
#define TDIM   10
#define HDIM   64
#define FCD    32
#define NHD    256
#define NROIF  300
#define NOTHER 127
#define ACTD   31
#define NSEQ   (NB*NROI)
#define COMB   1216
#define LOG2E  1.44269504f

typedef __attribute__((ext_vector_type(8))) short bf16x8;
typedef __attribute__((ext_vector_type(4))) float f32x4;
typedef __attribute__((ext_vector_type(2))) float f32x2;

// ---------------------------------------------------------------------------
// Correctness history (do not regress):
//  - R4/R5/R7/R8 corruption: CDNA TRANS-op use hazard — value-producing
//    inline asm (v_exp/v_rcp/v_pk_*) is invisible to LLVM's hazard
//    recognizer. Fix: intrinsics ONLY. No value-producing inline asm.
//  - R9 perf cliff: __launch_bounds__(256,5) + schedulable builtins =>
//    GB-scale scratch spills (FETCH_SIZE 74MB -> 3.6GB). Keep (256,4);
//    watch FETCH_SIZE + VGPR_Count on any reg-pressure change.
//  - v_cvt_pk_bf16_f32 is not RNE; use explicit f2bf for recurrence state.
// ---------------------------------------------------------------------------
#if __has_builtin(__builtin_amdgcn_exp2f)
__device__ __forceinline__ float fexp2(float x){ return __builtin_amdgcn_exp2f(x); }
#else
__device__ __forceinline__ float fexp2(float x){ return exp2f(x); }
#endif
#if __has_builtin(__builtin_amdgcn_rcpf)
__device__ __forceinline__ float frcp(float x){ return __builtin_amdgcn_rcpf(x); }
#else
__device__ __forceinline__ float frcp(float x){ return 1.0f / x; }
#endif
__device__ __forceinline__ f32x2 exp2v(f32x2 v){ f32x2 r; r.x = fexp2(v.x); r.y = fexp2(v.y); return r; }

// RNE f32->bf16
__device__ __forceinline__ short f2bf(float f) {
    unsigned u = __builtin_bit_cast(unsigned, f);
    u += 0x7fff + ((u >> 16) & 1);
    return (short)(u >> 16);
}
__device__ __forceinline__ float bf2f(short s) {
    return __builtin_bit_cast(float, ((unsigned)(unsigned short)s) << 16);
}

// ---------------------------------------------------------------------------
// MLP layer via MFMA: out[M][256] = relu(in[M][K] @ W^T + b).
// Block = 64 rows x 64 cols, 4 waves; wave w owns cols w*16..w*16+15.
// Fragment mapping copied verbatim from the verified LSTM GEMM:
//   D row = mt*16 + kq*4 + r, col = n0 (lane&15); A row = mt*16+n0,
//   k = kq*8..+7 per lane; chunk-XOR swizzle on the A LDS tile.
// A staged fp32->bf16 into LDS; B converted from fp32 global per K-step
// (L2-hot); bias rides in the MFMA C operand; K padded with zero B-frags
// so junk A elements cancel (A also guarded to avoid OOB at buffer end).
// ---------------------------------------------------------------------------
template<int KDIM>
__global__ __launch_bounds__(256) void mlp_mfma(
    const float* __restrict__ in, int ld_in,
    const float* __restrict__ W, const float* __restrict__ bias,
    float* __restrict__ out, int ld_out)
{
    __shared__ short A_lds[64 * 32];   // 4 KB, chunk-swizzled bf16

    const int tid  = threadIdx.x;
    const int w    = tid >> 6;
    const int lane = tid & 63;
    const int n0   = lane & 15;
    const int kq   = lane >> 4;
    const int m0   = blockIdx.x * 64;
    const int nb   = blockIdx.y * 64;
    const int n    = nb + w * 16 + n0;

    const int sm = tid >> 2;   // staging row 0..63
    const int sc = tid & 3;    // staging chunk 0..3

    f32x4 acc[4];
    {
        const float b = bias[n];
        #pragma unroll
        for (int mt = 0; mt < 4; mt++) {
            acc[mt][0] = b; acc[mt][1] = b; acc[mt][2] = b; acc[mt][3] = b;
        }
    }

    constexpr int KSTEPS = (KDIM + 31) / 32;
    for (int ks = 0; ks < KSTEPS; ks++) {
        const int k0 = ks * 32;

        // ---- stage A tile [64][32] fp32 -> bf16 (swizzled) ----
        {
            const float* src = in + (size_t)(m0 + sm) * ld_in + k0 + sc * 8;
            bf16x8 pk;
            #pragma unroll
            for (int j = 0; j < 8; j++) {
                float v = 0.0f;
                if ((KDIM % 32 == 0) || (k0 + sc * 8 + j < KDIM)) v = src[j];
                pk[j] = f2bf(v);
            }
            *(bf16x8*)&A_lds[sm * 32 + ((sc ^ (sm & 3)) << 3)] = pk;
        }
        __syncthreads();

        // ---- B fragment from fp32 global (zero-padded past KDIM) ----
        bf16x8 bf;
        {
            const float* wsrc = W + (size_t)n * KDIM + k0 + kq * 8;
            #pragma unroll
            for (int j = 0; j < 8; j++) {
                float v = 0.0f;
                if ((KDIM % 32 == 0) || (k0 + kq * 8 + j < KDIM)) v = wsrc[j];
                bf[j] = f2bf(v);
            }
        }

        // ---- 4 MFMAs (one per mtile) ----
        #pragma unroll
        for (int mt = 0; mt < 4; mt++) {
            const int ma = mt * 16 + n0;
            bf16x8 af = *(const bf16x8*)&A_lds[ma * 32 + ((kq ^ (ma & 3)) << 3)];
            acc[mt] = __builtin_amdgcn_mfma_f32_16x16x32_bf16(af, bf, acc[mt], 0, 0, 0);
        }
        __syncthreads();   // before next staging overwrites A_lds
    }

    // ---- epilogue: relu + store ----
    #pragma unroll
    for (int mt = 0; mt < 4; mt++) {
        #pragma unroll
        for (int r = 0; r < 4; r++) {
            const int m = m0 + mt * 16 + kq * 4 + r;
            float v = acc[mt][r];
            out[(size_t)m * ld_out + n] = v > 0.0f ? v : 0.0f;
        }
    }
}

// ---------------------------------------------------------------------------
// Fused bidirectional LSTM + FC, MFMA + f32x2 cell math.
// Byte-identical to R10 (PASS, 936us): builtins, (256,4), RNE writeback.
// ---------------------------------------------------------------------------
__global__ __launch_bounds__(256, 4) void lstm_fc_mfma(
    const float* __restrict__ x,
    const float* __restrict__ Wih_f, const float* __restrict__ Whh_f,
    const float* __restrict__ bih_f, const float* __restrict__ bhh_f,
    const float* __restrict__ Wih_b, const float* __restrict__ Whh_b,
    const float* __restrict__ bih_b, const float* __restrict__ bhh_b,
    const float* __restrict__ Wfc, const float* __restrict__ bfc,
    float* __restrict__ combined)
{
    __shared__ short Hbuf[3][64 * 64];   // 24 KB
    __shared__ float Xs[TDIM][64];       // 2.5 KB
    __shared__ int   lens_s[64];

    const int tid    = threadIdx.x;
    const int w      = tid >> 6;
    const int lane   = tid & 63;
    const int n0     = lane & 15;
    const int kq     = lane >> 4;
    const int s0base = blockIdx.x * 64;

    for (int idx = tid; idx < 64 * TDIM; idx += 256) {
        int s = idx & 63, t = idx >> 6;
        int gs = s0base + s;
        int row = gs / NROI, r = gs - row * NROI;
        Xs[t][s] = x[(size_t)row * NTOT + r * TDIM + t];
    }
    __syncthreads();
    if (tid < 64) {
        int c = 0;
        #pragma unroll
        for (int t = 0; t < TDIM; t++) c += (Xs[t][tid] != 0.0f) ? 1 : 0;
        lens_s[tid] = c;
    }
    for (int idx = tid; idx < 64 * 64; idx += 256) {
        Hbuf[0][idx] = 0; Hbuf[2][idx] = 0;
    }
    __syncthreads();

    int lenpk[8];
    #pragma unroll
    for (int i = 0; i < 8; i++) {
        const int c0 = 2 * i, c1 = 2 * i + 1;
        const int mA = (c0 >> 2) * 16 + kq * 4 + (c0 & 3);
        const int mB = (c1 >> 2) * 16 + kq * 4 + (c1 & 3);
        lenpk[i] = lens_s[mA] | (lens_s[mB] << 16);
    }

    const int ubase = w * 16 + n0;
    const int uhi = ubase >> 3, ulo = ubase & 7;

    for (int dir = 0; dir < 2; dir++) {
        const float* Whh  = dir ? Whh_b : Whh_f;
        const float* Wih  = dir ? Wih_b : Wih_f;
        const float* bihp = dir ? bih_b : bih_f;
        const float* bhhp = dir ? bhh_b : bhh_f;
        short* bufE = Hbuf[dir ? 2 : 0];
        short* bufO = Hbuf[1];

        const float sc0 = -LOG2E, sc2 = 2.0f * LOG2E;

        bf16x8 bfrag[4][2];
        float  wihS[4];
        f32x4  cinq[4];
        #pragma unroll
        for (int q = 0; q < 4; q++) {
            const float s_q = (q == 2) ? sc2 : sc0;
            const int n = (q * 4 + w) * 16 + n0;
            wihS[q] = s_q * Wih[n];
            const float bb = s_q * (bihp[n] + bhhp[n]);
            cinq[q][0] = bb; cinq[q][1] = bb; cinq[q][2] = bb; cinq[q][3] = bb;
            #pragma unroll
            for (int half = 0; half < 2; half++) {
                const float* src = Whh + (size_t)n * HDIM + half * 32 + kq * 8;
                bf16x8 f;
                #pragma unroll
                for (int j = 0; j < 8; j++) f[j] = f2bf(s_q * src[j]);
                bfrag[q][half] = f;
            }
        }

        f32x2 c2[8];
        #pragma unroll
        for (int i = 0; i < 8; i++) { c2[i].x = 0.0f; c2[i].y = 0.0f; }

        for (int step = 0; step < TDIM; step++) {
            const int t = dir ? (TDIM - 1 - step) : step;
            short* rb = (step & 1) ? bufO : bufE;
            short* wb = (step & 1) ? bufE : bufO;

            #pragma unroll
            for (int mt = 0; mt < 4; mt++) {
                const int ma = mt * 16 + n0;
                const int sa = ma & 7;
                bf16x8 a0 = *(const bf16x8*)&rb[ma * 64 + ((kq ^ sa) << 3)];
                bf16x8 a1 = *(const bf16x8*)&rb[ma * 64 + (((4 + kq) ^ sa) << 3)];

                f32x4 acc[4];
                #pragma unroll
                for (int q = 0; q < 4; q++) {
                    f32x4 p = __builtin_amdgcn_mfma_f32_16x16x32_bf16(a0, bfrag[q][0], cinq[q], 0, 0, 0);
                    acc[q] = __builtin_amdgcn_mfma_f32_16x16x32_bf16(a1, bfrag[q][1], p, 0, 0, 0);
                }

                #pragma unroll
                for (int pr = 0; pr < 2; pr++) {
                    const int r0  = 2 * pr;
                    const int mm  = mt * 16 + kq * 4 + r0;
                    const int lp  = lenpk[mt * 2 + pr];
                    const bool m0 = t < (lp & 0xffff);
                    const bool m1 = t < (lp >> 16);

                    f32x2 xv2 = *(const f32x2*)&Xs[t][mm];
                    f32x2 a_i = {acc[0][r0], acc[0][r0 + 1]};
                    f32x2 a_f = {acc[1][r0], acc[1][r0 + 1]};
                    f32x2 a_g = {acc[2][r0], acc[2][r0 + 1]};
                    f32x2 a_o = {acc[3][r0], acc[3][r0 + 1]};

                    f32x2 ei = exp2v(a_i + xv2 * wihS[0]);
                    f32x2 ef = exp2v(a_f + xv2 * wihS[1]);
                    f32x2 eg = exp2v(a_g + xv2 * wihS[2]);
                    f32x2 eo = exp2v(a_o + xv2 * wihS[3]);

                    f32x2 di = ei + 1.0f;
                    f32x2 df = ef + 1.0f;
                    f32x2 dg = eg + 1.0f;
                    f32x2 dd = eo + 1.0f;

                    f32x2 t1 = di * df;
                    f32x2 t2 = dd * dg;
                    f32x2 P  = t1 * t2;
                    f32x2 R; R.x = frcp(P.x); R.y = frcp(P.y);
                    f32x2 R12 = R * t2;
                    f32x2 R34 = R * t1;
                    f32x2 si  = R12 * df;
                    f32x2 sf  = R12 * di;
                    f32x2 so  = R34 * dg;
                    f32x2 ig  = R34 * dd;
                    f32x2 tg  = 1.0f - 2.0f * ig;

                    f32x2 cp = c2[mt * 2 + pr];
                    f32x2 cn = si * tg + sf * cp;
                    f32x2 cf;
                    cf.x = m0 ? cn.x : cp.x;
                    cf.y = m1 ? cn.y : cp.y;
                    c2[mt * 2 + pr] = cf;

                    f32x2 ec = exp2v(cf * (2.0f * LOG2E));
                    f32x2 dc = ec + 1.0f;
                    float Pc = dc.x * dc.y;
                    float Rc = frcp(Pc);
                    f32x2 invc; invc.x = Rc * dc.y; invc.y = Rc * dc.x;
                    f32x2 tc = 1.0f - 2.0f * invc;
                    f32x2 hn = so * tc;

                    const int hidx0 = (mm << 6)       + (((uhi ^ mm) & 7) << 3)       + ulo;
                    const int hidx1 = ((mm + 1) << 6) + (((uhi ^ (mm + 1)) & 7) << 3) + ulo;
                    float h0 = m0 ? hn.x : bf2f(rb[hidx0]);
                    float h1 = m1 ? hn.y : bf2f(rb[hidx1]);
                    wb[hidx0] = f2bf(h0);
                    wb[hidx1] = f2bf(h1);
                }
            }
            __syncthreads();
        }
    }

    __builtin_amdgcn_sched_barrier(0);

    // ---- FC epilogue as MFMA: D[64s x 32f] = [Hf|Hb][64x128] @ Wfc^T ----
    {
        const short* Hf = Hbuf[0];
        const short* Hb = Hbuf[2];

        bf16x8 wfr[2][4];
        float  bias[2];
        #pragma unroll
        for (int nt = 0; nt < 2; nt++) {
            const int f = nt * 16 + n0;
            bias[nt] = bfc[f];
            #pragma unroll
            for (int kc = 0; kc < 4; kc++) {
                const float* src = Wfc + (size_t)f * 128 + kc * 32 + kq * 8;
                bf16x8 v;
                #pragma unroll
                for (int j = 0; j < 8; j++) v[j] = f2bf(src[j]);
                wfr[nt][kc] = v;
            }
        }

        const int ma = w * 16 + n0;
        const int sa = ma & 7;
        bf16x8 afr[4];
        #pragma unroll
        for (int kc = 0; kc < 2; kc++) {
            afr[kc]     = *(const bf16x8*)&Hf[ma * 64 + (((kc * 4 + kq) ^ sa) << 3)];
            afr[kc + 2] = *(const bf16x8*)&Hb[ma * 64 + (((kc * 4 + kq) ^ sa) << 3)];
        }

        f32x4 acc[2];
        #pragma unroll
        for (int nt = 0; nt < 2; nt++) {
            f32x4 z = {0.0f, 0.0f, 0.0f, 0.0f};
            acc[nt] = z;
            #pragma unroll
            for (int kc = 0; kc < 4; kc++)
                acc[nt] = __builtin_amdgcn_mfma_f32_16x16x32_bf16(afr[kc], wfr[nt][kc], acc[nt], 0, 0, 0);
        }

        #pragma unroll
        for (int nt = 0; nt < 2; nt++) {
            #pragma unroll
            for (int r = 0; r < 4; r++) {
                const int s   = w * 16 + kq * 4 + r;
                const int gs  = s0base + s;
                const int row = gs / NROI, rr = gs - row * NROI;
                float v = acc[nt][r] + bias[nt];
                combined[(size_t)row * COMB + rr * FCD + nt * 16 + n0] = v > 0.0f ? v : 0.0f;
            }
        }
    }
}

// ---------------------------------------------------------------------------
// Output projection: q[row][j] = b_out[j] + combined[row] . W_out[j]
// (unchanged from R10)
// ---------------------------------------------------------------------------
__global__ __launch_bounds__(256) void qout_kernel(
    const float* __restrict__ combined,
    const float* __restrict__ Wout,
    const float* __restrict__ bout,
    float* __restrict__ q)
{
    const int j   = threadIdx.x;              // 0..31 (31 masked)
    const int r   = threadIdx.y;              // 0..7
    const int row = blockIdx.x * 8 + r;
    if (j >= ACTD) return;
    const float4* crow = (const float4*)(combined + (size_t)row * COMB);
    const float4* wrow = (const float4*)(Wout + (size_t)j * COMB);
    float acc = bout[j];
    #pragma unroll 4
    for (int k4 = 0; k4 < COMB / 4; k4++) {
        float4 c4 = crow[k4];
        float4 w4 = wrow[k4];
        acc += c4.x * w4.x + c4.y * w4.y + c4.z * w4.z + c4.w * w4.w;
    }
    q[(size_t)row * ACTD + j] = acc;
}

// ---------------------------------------------------------------------------
extern "C" void kernel_launch(void* const* d_in, const int* in_sizes, int n_in,
                              void* d_out, int out_size, void* d_ws, size_t ws_size,
                              hipStream_t stream)
{
    (void)in_sizes; (void)n_in; (void)out_size;
    const float* x     = (const float*)d_in[0];
    const float* Wih_f = (const float*)d_in[1];
    const float* Whh_f = (const float*)d_in[2];
    const float* bih_f = (const float*)d_in[3];
    const float* bhh_f = (const float*)d_in[4];
    const float* Wih_b = (const float*)d_in[5];
    const float* Whh_b = (const float*)d_in[6];
    const float* bih_b = (const float*)d_in[7];
    const float* bhh_b = (const float*)d_in[8];
    const float* Wfc   = (const float*)d_in[9];
    const float* bfc   = (const float*)d_in[10];
    const float* W1    = (const float*)d_in[11];
    const float* b1    = (const float*)d_in[12];
    const float* W2    = (const float*)d_in[13];
    const float* b2    = (const float*)d_in[14];
    const float* W3    = (const float*)d_in[15];
    const float* b3    = (const float*)d_in[16];
    const float* Wout  = (const float*)d_in[17];
    const float* bout  = (const float*)d_in[18];
    float* q        = (float*)d_out;
    float* combined = (float*)d_ws;   // 16384 x 1216 f32 = 79.7 MB

    if (ws_size < (size_t)NB * COMB * sizeof(float)) return;

    // MLP via MFMA: h1 -> cols[0,256), h2 -> [256,512), out -> [960,1216).
    dim3 gmlp(NB / 64, NHD / 64);   // 256 x 4 = 1024 blocks
    mlp_mfma<NOTHER><<<gmlp, 256, 0, stream>>>(x + NROIF, NTOT, W1, b1, combined, COMB);
    mlp_mfma<NHD><<<gmlp, 256, 0, stream>>>(combined, COMB, W2, b2, combined + 256, COMB);
    mlp_mfma<NHD><<<gmlp, 256, 0, stream>>>(combined + 256, COMB, W3, b3, combined + 960, COMB);

    lstm_fc_mfma<<<NSEQ / 64, 256, 0, stream>>>(x, Wih_f, Whh_f, bih_f, bhh_f,
                                                Wih_b, Whh_b, bih_b, bhh_b,
                                                Wfc, bfc, combined);

    qout_kernel<<<NB / 8, dim3(32, 8), 0, stream>>>(combined, Wout, bout, q);
}

// Round 12
// 1140.349 us; speedup vs baseline: 1.9671x; 1.0148x over previous
//
#include <hip/hip_runtime.h>
#include <math.h>

#define NB     16384
#define NTOT   427
#define NROI   30
#define TDIM   10
#define HDIM   64
#define FCD    32
#define NHD    256
#define NROIF  300
#define NOTHER 127
#define ACTD   31
#define NSEQ   (NB*NROI)
#define COMB   1216
#define LOG2E  1.44269504f

typedef __attribute__((ext_vector_type(8))) short bf16x8;
typedef __attribute__((ext_vector_type(4))) float f32x4;
typedef __attribute__((ext_vector_type(2))) float f32x2;

// ---------------------------------------------------------------------------
// Correctness / perf history (do not regress):
//  - R4/R5/R7/R8 corruption: CDNA TRANS-op use hazard — value-producing
//    inline asm is invisible to LLVM's hazard recognizer. Intrinsics ONLY.
//  - R9 cliff: (256,5) cap => GB-scale scratch spills. Keep (256,4); watch
//    FETCH_SIZE (+VGPR_Count) on any reg-pressure change.
//  - Occupancy model (R9 vs R10/R11 data): waves/CU = 1024/VGPR, block
//    granular. VGPR 64 -> 16 waves; <=51 -> 20 waves. R12 targets <=51 by
//    cutting 18 regs of state (lenpk 4-bit pack, cinq->scalar bias).
//  - f32->bf16 for recurrence state must be RNE: native __bf16 cast
//    (compiler-known fptrunc) — NOT hand inline asm.
// ---------------------------------------------------------------------------
#if __has_builtin(__builtin_amdgcn_exp2f)
__device__ __forceinline__ float fexp2(float x){ return __builtin_amdgcn_exp2f(x); }
#else
__device__ __forceinline__ float fexp2(float x){ return exp2f(x); }
#endif
#if __has_builtin(__builtin_amdgcn_rcpf)
__device__ __forceinline__ float frcp(float x){ return __builtin_amdgcn_rcpf(x); }
#else
__device__ __forceinline__ float frcp(float x){ return 1.0f / x; }
#endif
__device__ __forceinline__ f32x2 exp2v(f32x2 v){ f32x2 r; r.x = fexp2(v.x); r.y = fexp2(v.y); return r; }

// RNE f32->bf16 via native conversion (compiler-known, hazard-safe)
__device__ __forceinline__ short f2bf(float f) {
    return __builtin_bit_cast(short, (__bf16)f);
}
__device__ __forceinline__ float bf2f(short s) {
    return __builtin_bit_cast(float, ((unsigned)(unsigned short)s) << 16);
}

// ---------------------------------------------------------------------------
// MLP layer via MFMA (unchanged from R11, PASS).
// ---------------------------------------------------------------------------
template<int KDIM>
__global__ __launch_bounds__(256) void mlp_mfma(
    const float* __restrict__ in, int ld_in,
    const float* __restrict__ W, const float* __restrict__ bias,
    float* __restrict__ out, int ld_out)
{
    __shared__ short A_lds[64 * 32];   // 4 KB, chunk-swizzled bf16

    const int tid  = threadIdx.x;
    const int w    = tid >> 6;
    const int lane = tid & 63;
    const int n0   = lane & 15;
    const int kq   = lane >> 4;
    const int m0   = blockIdx.x * 64;
    const int nb   = blockIdx.y * 64;
    const int n    = nb + w * 16 + n0;

    const int sm = tid >> 2;
    const int sc = tid & 3;

    f32x4 acc[4];
    {
        const float b = bias[n];
        #pragma unroll
        for (int mt = 0; mt < 4; mt++) {
            acc[mt][0] = b; acc[mt][1] = b; acc[mt][2] = b; acc[mt][3] = b;
        }
    }

    constexpr int KSTEPS = (KDIM + 31) / 32;
    for (int ks = 0; ks < KSTEPS; ks++) {
        const int k0 = ks * 32;
        {
            const float* src = in + (size_t)(m0 + sm) * ld_in + k0 + sc * 8;
            bf16x8 pk;
            #pragma unroll
            for (int j = 0; j < 8; j++) {
                float v = 0.0f;
                if ((KDIM % 32 == 0) || (k0 + sc * 8 + j < KDIM)) v = src[j];
                pk[j] = f2bf(v);
            }
            *(bf16x8*)&A_lds[sm * 32 + ((sc ^ (sm & 3)) << 3)] = pk;
        }
        __syncthreads();

        bf16x8 bf;
        {
            const float* wsrc = W + (size_t)n * KDIM + k0 + kq * 8;
            #pragma unroll
            for (int j = 0; j < 8; j++) {
                float v = 0.0f;
                if ((KDIM % 32 == 0) || (k0 + kq * 8 + j < KDIM)) v = wsrc[j];
                bf[j] = f2bf(v);
            }
        }

        #pragma unroll
        for (int mt = 0; mt < 4; mt++) {
            const int ma = mt * 16 + n0;
            bf16x8 af = *(const bf16x8*)&A_lds[ma * 32 + ((kq ^ (ma & 3)) << 3)];
            acc[mt] = __builtin_amdgcn_mfma_f32_16x16x32_bf16(af, bf, acc[mt], 0, 0, 0);
        }
        __syncthreads();
    }

    #pragma unroll
    for (int mt = 0; mt < 4; mt++) {
        #pragma unroll
        for (int r = 0; r < 4; r++) {
            const int m = m0 + mt * 16 + kq * 4 + r;
            float v = acc[mt][r];
            out[(size_t)m * ld_out + n] = v > 0.0f ? v : 0.0f;
        }
    }
}

// ---------------------------------------------------------------------------
// Fused bidirectional LSTM + FC. R12 deltas vs R11 (all targeting VGPR<=51):
//  - lens packed 4-bit (2 regs instead of 8)
//  - bias as 4 scalars added in cell math; MFMA C starts at zero (-12 regs)
//  - native __bf16 casts for h writeback; mask-hold select at short level
// ---------------------------------------------------------------------------
__global__ __launch_bounds__(256, 4) void lstm_fc_mfma(
    const float* __restrict__ x,
    const float* __restrict__ Wih_f, const float* __restrict__ Whh_f,
    const float* __restrict__ bih_f, const float* __restrict__ bhh_f,
    const float* __restrict__ Wih_b, const float* __restrict__ Whh_b,
    const float* __restrict__ bih_b, const float* __restrict__ bhh_b,
    const float* __restrict__ Wfc, const float* __restrict__ bfc,
    float* __restrict__ combined)
{
    __shared__ short Hbuf[3][64 * 64];   // 24 KB
    __shared__ float Xs[TDIM][64];       // 2.5 KB
    __shared__ int   lens_s[64];

    const int tid    = threadIdx.x;
    const int w      = tid >> 6;
    const int lane   = tid & 63;
    const int n0     = lane & 15;
    const int kq     = lane >> 4;
    const int s0base = blockIdx.x * 64;

    for (int idx = tid; idx < 64 * TDIM; idx += 256) {
        int s = idx & 63, t = idx >> 6;
        int gs = s0base + s;
        int row = gs / NROI, r = gs - row * NROI;
        Xs[t][s] = x[(size_t)row * NTOT + r * TDIM + t];
    }
    __syncthreads();
    if (tid < 64) {
        int c = 0;
        #pragma unroll
        for (int t = 0; t < TDIM; t++) c += (Xs[t][tid] != 0.0f) ? 1 : 0;
        lens_s[tid] = c;
    }
    for (int idx = tid; idx < 64 * 64; idx += 256) {
        Hbuf[0][idx] = 0; Hbuf[2][idx] = 0;
    }
    __syncthreads();

    // 4-bit packed lens: cell i (i=0..15, mt=i>>2, r=i&3) -> reg i>>3, nibble i&7
    unsigned lpk[2];
    {
        unsigned p0 = 0, p1 = 0;
        #pragma unroll
        for (int i = 0; i < 16; i++) {
            const int mi = (i >> 2) * 16 + kq * 4 + (i & 3);
            const unsigned v = (unsigned)lens_s[mi];
            if (i < 8) p0 |= v << (4 * i);
            else       p1 |= v << (4 * (i - 8));
        }
        lpk[0] = p0; lpk[1] = p1;
    }

    const int ubase = w * 16 + n0;
    const int uhi = ubase >> 3, ulo = ubase & 7;
    const f32x4 zq = {0.0f, 0.0f, 0.0f, 0.0f};

    for (int dir = 0; dir < 2; dir++) {
        const float* Whh  = dir ? Whh_b : Whh_f;
        const float* Wih  = dir ? Wih_b : Wih_f;
        const float* bihp = dir ? bih_b : bih_f;
        const float* bhhp = dir ? bhh_b : bhh_f;
        short* bufE = Hbuf[dir ? 2 : 0];
        short* bufO = Hbuf[1];

        const float sc0 = -LOG2E, sc2 = 2.0f * LOG2E;

        bf16x8 bfrag[4][2];
        float  wihS[4];
        float  bb[4];
        #pragma unroll
        for (int q = 0; q < 4; q++) {
            const float s_q = (q == 2) ? sc2 : sc0;
            const int n = (q * 4 + w) * 16 + n0;
            wihS[q] = s_q * Wih[n];
            bb[q]   = s_q * (bihp[n] + bhhp[n]);
            #pragma unroll
            for (int half = 0; half < 2; half++) {
                const float* src = Whh + (size_t)n * HDIM + half * 32 + kq * 8;
                bf16x8 f;
                #pragma unroll
                for (int j = 0; j < 8; j++) f[j] = f2bf(s_q * src[j]);
                bfrag[q][half] = f;
            }
        }

        f32x2 c2[8];
        #pragma unroll
        for (int i = 0; i < 8; i++) { c2[i].x = 0.0f; c2[i].y = 0.0f; }

        for (int step = 0; step < TDIM; step++) {
            const int t = dir ? (TDIM - 1 - step) : step;
            short* rb = (step & 1) ? bufO : bufE;
            short* wb = (step & 1) ? bufE : bufO;

            #pragma unroll
            for (int mt = 0; mt < 4; mt++) {
                const int ma = mt * 16 + n0;
                const int sa = ma & 7;
                bf16x8 a0 = *(const bf16x8*)&rb[ma * 64 + ((kq ^ sa) << 3)];
                bf16x8 a1 = *(const bf16x8*)&rb[ma * 64 + (((4 + kq) ^ sa) << 3)];

                f32x4 acc[4];
                #pragma unroll
                for (int q = 0; q < 4; q++) {
                    f32x4 p = __builtin_amdgcn_mfma_f32_16x16x32_bf16(a0, bfrag[q][0], zq, 0, 0, 0);
                    acc[q] = __builtin_amdgcn_mfma_f32_16x16x32_bf16(a1, bfrag[q][1], p, 0, 0, 0);
                }

                #pragma unroll
                for (int pr = 0; pr < 2; pr++) {
                    const int r0  = 2 * pr;
                    const int mm  = mt * 16 + kq * 4 + r0;
                    const int c0  = mt * 4 + r0;          // cell index 0..15
                    const unsigned lreg = lpk[c0 >> 3];
                    const int len0 = (lreg >> (4 * (c0 & 7))) & 0xF;
                    const int len1 = (lreg >> (4 * ((c0 + 1) & 7))) & 0xF;
                    const bool m0 = t < len0;
                    const bool m1 = t < len1;

                    f32x2 xv2 = *(const f32x2*)&Xs[t][mm];
                    f32x2 a_i = {acc[0][r0], acc[0][r0 + 1]};
                    f32x2 a_f = {acc[1][r0], acc[1][r0 + 1]};
                    f32x2 a_g = {acc[2][r0], acc[2][r0 + 1]};
                    f32x2 a_o = {acc[3][r0], acc[3][r0 + 1]};

                    // scaled gates -> exp2 directly; bias added here (scalar bb)
                    f32x2 ei = exp2v(a_i + (xv2 * wihS[0] + bb[0]));
                    f32x2 ef = exp2v(a_f + (xv2 * wihS[1] + bb[1]));
                    f32x2 eg = exp2v(a_g + (xv2 * wihS[2] + bb[2]));
                    f32x2 eo = exp2v(a_o + (xv2 * wihS[3] + bb[3]));

                    f32x2 di = ei + 1.0f;
                    f32x2 df = ef + 1.0f;
                    f32x2 dg = eg + 1.0f;
                    f32x2 dd = eo + 1.0f;

                    // batched reciprocal: 1 rcp per cell for 4 denominators
                    f32x2 t1 = di * df;
                    f32x2 t2 = dd * dg;
                    f32x2 P  = t1 * t2;
                    f32x2 R; R.x = frcp(P.x); R.y = frcp(P.y);
                    f32x2 R12 = R * t2;
                    f32x2 R34 = R * t1;
                    f32x2 si  = R12 * df;
                    f32x2 sf  = R12 * di;
                    f32x2 so  = R34 * dg;
                    f32x2 ig  = R34 * dd;
                    f32x2 tg  = 1.0f - 2.0f * ig;

                    f32x2 cp = c2[mt * 2 + pr];
                    f32x2 cn = si * tg + sf * cp;
                    f32x2 cf;
                    cf.x = m0 ? cn.x : cp.x;
                    cf.y = m1 ? cn.y : cp.y;
                    c2[mt * 2 + pr] = cf;

                    // tanh(c) with pair-batched rcp
                    f32x2 ec = exp2v(cf * (2.0f * LOG2E));
                    f32x2 dc = ec + 1.0f;
                    float Pc = dc.x * dc.y;
                    float Rc = frcp(Pc);
                    f32x2 invc; invc.x = Rc * dc.y; invc.y = Rc * dc.x;
                    f32x2 tc = 1.0f - 2.0f * invc;
                    f32x2 hn = so * tc;

                    const int hidx0 = (mm << 6)       + (((uhi ^ mm) & 7) << 3)       + ulo;
                    const int hidx1 = ((mm + 1) << 6) + (((uhi ^ (mm + 1)) & 7) << 3) + ulo;
                    const short s0 = f2bf(hn.x);
                    const short s1 = f2bf(hn.y);
                    wb[hidx0] = m0 ? s0 : rb[hidx0];   // hold at bf16 level
                    wb[hidx1] = m1 ? s1 : rb[hidx1];
                }
            }
            __syncthreads();   // wb complete before it becomes next step's rb
        }
        // final h of this dir is in bufE (step 9 writes bufE)
    }

    __builtin_amdgcn_sched_barrier(0);

    // ---- FC epilogue as MFMA: D[64s x 32f] = [Hf|Hb][64x128] @ Wfc^T ----
    {
        const short* Hf = Hbuf[0];
        const short* Hb = Hbuf[2];

        bf16x8 wfr[2][4];
        float  bias[2];
        #pragma unroll
        for (int nt = 0; nt < 2; nt++) {
            const int f = nt * 16 + n0;
            bias[nt] = bfc[f];
            #pragma unroll
            for (int kc = 0; kc < 4; kc++) {
                const float* src = Wfc + (size_t)f * 128 + kc * 32 + kq * 8;
                bf16x8 v;
                #pragma unroll
                for (int j = 0; j < 8; j++) v[j] = f2bf(src[j]);
                wfr[nt][kc] = v;
            }
        }

        const int ma = w * 16 + n0;
        const int sa = ma & 7;
        bf16x8 afr[4];
        #pragma unroll
        for (int kc = 0; kc < 2; kc++) {
            afr[kc]     = *(const bf16x8*)&Hf[ma * 64 + (((kc * 4 + kq) ^ sa) << 3)];
            afr[kc + 2] = *(const bf16x8*)&Hb[ma * 64 + (((kc * 4 + kq) ^ sa) << 3)];
        }

        f32x4 acc[2];
        #pragma unroll
        for (int nt = 0; nt < 2; nt++) {
            f32x4 z = {0.0f, 0.0f, 0.0f, 0.0f};
            acc[nt] = z;
            #pragma unroll
            for (int kc = 0; kc < 4; kc++)
                acc[nt] = __builtin_amdgcn_mfma_f32_16x16x32_bf16(afr[kc], wfr[nt][kc], acc[nt], 0, 0, 0);
        }

        #pragma unroll
        for (int nt = 0; nt < 2; nt++) {
            #pragma unroll
            for (int r = 0; r < 4; r++) {
                const int s   = w * 16 + kq * 4 + r;
                const int gs  = s0base + s;
                const int row = gs / NROI, rr = gs - row * NROI;
                float v = acc[nt][r] + bias[nt];
                combined[(size_t)row * COMB + rr * FCD + nt * 16 + n0] = v > 0.0f ? v : 0.0f;
            }
        }
    }
}

// ---------------------------------------------------------------------------
// Output projection (unchanged).
// ---------------------------------------------------------------------------
__global__ __launch_bounds__(256) void qout_kernel(
    const float* __restrict__ combined,
    const float* __restrict__ Wout,
    const float* __restrict__ bout,
    float* __restrict__ q)
{
    const int j   = threadIdx.x;
    const int r   = threadIdx.y;
    const int row = blockIdx.x * 8 + r;
    if (j >= ACTD) return;
    const float4* crow = (const float4*)(combined + (size_t)row * COMB);
    const float4* wrow = (const float4*)(Wout + (size_t)j * COMB);
    float acc = bout[j];
    #pragma unroll 4
    for (int k4 = 0; k4 < COMB / 4; k4++) {
        float4 c4 = crow[k4];
        float4 w4 = wrow[k4];
        acc += c4.x * w4.x + c4.y * w4.y + c4.z * w4.z + c4.w * w4.w;
    }
    q[(size_t)row * ACTD + j] = acc;
}

// ---------------------------------------------------------------------------
extern "C" void kernel_launch(void* const* d_in, const int* in_sizes, int n_in,
                              void* d_out, int out_size, void* d_ws, size_t ws_size,
                              hipStream_t stream)
{
    (void)in_sizes; (void)n_in; (void)out_size;
    const float* x     = (const float*)d_in[0];
    const float* Wih_f = (const float*)d_in[1];
    const float* Whh_f = (const float*)d_in[2];
    const float* bih_f = (const float*)d_in[3];
    const float* bhh_f = (const float*)d_in[4];
    const float* Wih_b = (const float*)d_in[5];
    const float* Whh_b = (const float*)d_in[6];
    const float* bih_b = (const float*)d_in[7];
    const float* bhh_b = (const float*)d_in[8];
    const float* Wfc   = (const float*)d_in[9];
    const float* bfc   = (const float*)d_in[10];
    const float* W1    = (const float*)d_in[11];
    const float* b1    = (const float*)d_in[12];
    const float* W2    = (const float*)d_in[13];
    const float* b2    = (const float*)d_in[14];
    const float* W3    = (const float*)d_in[15];
    const float* b3    = (const float*)d_in[16];
    const float* Wout  = (const float*)d_in[17];
    const float* bout  = (const float*)d_in[18];
    float* q        = (float*)d_out;
    float* combined = (float*)d_ws;   // 16384 x 1216 f32 = 79.7 MB

    if (ws_size < (size_t)NB * COMB * sizeof(float)) return;

    dim3 gmlp(NB / 64, NHD / 64);
    mlp_mfma<NOTHER><<<gmlp, 256, 0, stream>>>(x + NROIF, NTOT, W1, b1, combined, COMB);
    mlp_mfma<NHD><<<gmlp, 256, 0, stream>>>(combined, COMB, W2, b2, combined + 256, COMB);
    mlp_mfma<NHD><<<gmlp, 256, 0, stream>>>(combined + 256, COMB, W3, b3, combined + 960, COMB);

    lstm_fc_mfma<<<NSEQ / 64, 256, 0, stream>>>(x, Wih_f, Whh_f, bih_f, bhh_f,
                                                Wih_b, Whh_b, bih_b, bhh_b,
                                                Wfc, bfc, combined);

    qout_kernel<<<NB / 8, dim3(32, 8), 0, stream>>>(combined, Wout, bout, q);
}